// Round 2
// baseline (422.706 us; speedup 1.0000x reference)
//
#include <hip/hip_runtime.h>

// out = X · M,  M = (W^T W) / 32  (symmetric 1024x1024)
// X: 65536x1024 fp32.  W: 1024x1024 fp32.  out: 65536x1024 fp32.
// Path A (ws >= 131 MB): prep kernel {X->bf16 convert ; M=W^T W} fused,
//   then m97-structure GEMM with global_load_lds for BOTH operands.
// Path B (small ws): R1's fused kernel (A reg-staged with cvt).

typedef unsigned short u16;
typedef unsigned int u32;
typedef __bf16 bf16x8 __attribute__((ext_vector_type(8)));
typedef float f32x4 __attribute__((ext_vector_type(4)));

__device__ __forceinline__ u16 f2bf(float f) {  // RNE fp32->bf16
  u32 u = __float_as_uint(f);
  u += 0x7fffu + ((u >> 16) & 1u);
  return (u16)(u >> 16);
}

__device__ __forceinline__ void gload_lds16(const void* g, void* l) {
  __builtin_amdgcn_global_load_lds((const __attribute__((address_space(1))) u32*)g,
                                   (__attribute__((address_space(3))) u32*)l,
                                   16, 0, 0);
}

// ---------------- prep: blocks [0,2048) convert X; [2048,2304) compute M ------
__global__ __launch_bounds__(256) void prep(const float* __restrict__ X,
                                            const float* __restrict__ W,
                                            u16* __restrict__ Xb,
                                            u16* __restrict__ Mb) {
  __shared__ float w1[32][64];
  __shared__ float w2[32][64];
  const int t = threadIdx.x;
  if (blockIdx.x < 2048) {
    // convert 64M floats; granularity float4 -> 4x bf16 (8B store), coalesced
    const size_t stride = 2048 * 256;
    size_t idx = (size_t)blockIdx.x * 256 + t;
#pragma unroll 4
    for (int it = 0; it < 32; ++it, idx += stride) {
      const float4 v = *(const float4*)(X + idx * 4);
      ushort4 d;
      d.x = f2bf(v.x); d.y = f2bf(v.y); d.z = f2bf(v.z); d.w = f2bf(v.w);
      *(ushort4*)(Xb + idx * 4) = d;
    }
    return;
  }
  // ---- M = (W^T W)/32, 64x64 tile per block ----
  const int mb = blockIdx.x - 2048;
  const int i0 = (mb >> 4) * 64;
  const int j0 = (mb & 15) * 64;
  const int tx = t & 15, ty = t >> 4;
  float acc[4][4] = {};
  for (int u0 = 0; u0 < 1024; u0 += 32) {
    __syncthreads();
#pragma unroll
    for (int p = 0; p < 2; ++p) {
      int idx = p * 256 + t;
      int lu = idx >> 4, lc = (idx & 15) * 4;
      *(float4*)&w1[lu][lc] = *(const float4*)(W + (size_t)(u0 + lu) * 1024 + i0 + lc);
      *(float4*)&w2[lu][lc] = *(const float4*)(W + (size_t)(u0 + lu) * 1024 + j0 + lc);
    }
    __syncthreads();
#pragma unroll 8
    for (int u = 0; u < 32; ++u) {
      float4 a = *(const float4*)&w1[u][ty * 4];
      float4 b = *(const float4*)&w2[u][tx * 4];
      float av[4] = {a.x, a.y, a.z, a.w};
      float bv[4] = {b.x, b.y, b.z, b.w};
#pragma unroll
      for (int e = 0; e < 4; ++e)
#pragma unroll
        for (int f = 0; f < 4; ++f)
          acc[e][f] += av[e] * bv[f];
    }
  }
  const float s = 0.03125f;
#pragma unroll
  for (int e = 0; e < 4; ++e) {
    ushort4 v;
    v.x = f2bf(acc[e][0] * s);
    v.y = f2bf(acc[e][1] * s);
    v.z = f2bf(acc[e][2] * s);
    v.w = f2bf(acc[e][3] * s);
    *(ushort4*)(Mb + (size_t)(i0 + ty * 4 + e) * 1024 + j0 + tx * 4) = v;
  }
}

// ---------------- GEMM (m97 structure): both operands via global_load_lds -----
// 128x128 tile, BK=32, 4 waves (2x2), 16x16x32 bf16 MFMA, chunk-XOR swizzle
// realized via pre-swizzled global source (LDS dest stays linear per-slot).
__global__ __launch_bounds__(256) void gemm_lds(const u16* __restrict__ Xb,
                                                const u16* __restrict__ Mb,
                                                float* __restrict__ out) {
  __shared__ u16 lA[128 * 32];
  __shared__ u16 lB[128 * 32];

  const int p = blockIdx.x;                 // chunked XCD swizzle (4096 = 8*512)
  const int wg = (p & 7) * 512 + (p >> 3);
  const int bm = wg >> 3;
  const int bn = wg & 7;
  const size_t r0 = (size_t)bm * 128;
  const int c0 = bn * 128;

  const int t = threadIdx.x;
  const int lane = t & 63;
  const int w = t >> 6;
  const int wr = w >> 1, wc = w & 1;

  const int fr = lane & 15;
  const int kc = lane >> 4;

  // per-wave staging slots (2 calls x 64 lanes each, per operand)
  const int slot0_0 = w * 128;
  const int slot0_1 = w * 128 + 64;
  const int slotA0 = slot0_0 + lane, slotA1 = slot0_1 + lane;
  const int arow0 = slotA0 >> 2, arow1 = slotA1 >> 2;
  const int acc0 = (slotA0 & 3) ^ ((arow0 >> 1) & 3);  // inverse-swizzled chunk
  const int acc1 = (slotA1 & 3) ^ ((arow1 >> 1) & 3);
  const u16* gA0 = Xb + (r0 + arow0) * 1024 + acc0 * 8;
  const u16* gA1 = Xb + (r0 + arow1) * 1024 + acc1 * 8;
  const u16* gB0 = Mb + (size_t)(c0 + arow0) * 1024 + acc0 * 8;
  const u16* gB1 = Mb + (size_t)(c0 + arow1) * 1024 + acc1 * 8;

  f32x4 acc[4][4] = {};

  for (int k0 = 0; k0 < 1024; k0 += 32) {
    gload_lds16(gA0 + k0, (void*)(lA + slot0_0 * 8));
    gload_lds16(gA1 + k0, (void*)(lA + slot0_1 * 8));
    gload_lds16(gB0 + k0, (void*)(lB + slot0_0 * 8));
    gload_lds16(gB1 + k0, (void*)(lB + slot0_1 * 8));
    __syncthreads();  // drains vmcnt -> LDS tiles ready
    bf16x8 afr[4], bfr[4];
#pragma unroll
    for (int m = 0; m < 4; ++m) {
      const int row = wr * 64 + m * 16 + fr;
      const int cs = kc ^ ((row >> 1) & 3);
      afr[m] = *(const bf16x8*)&lA[row * 32 + cs * 8];
    }
#pragma unroll
    for (int n = 0; n < 4; ++n) {
      const int row = wc * 64 + n * 16 + fr;
      const int cs = kc ^ ((row >> 1) & 3);
      bfr[n] = *(const bf16x8*)&lB[row * 32 + cs * 8];
    }
#pragma unroll
    for (int m = 0; m < 4; ++m)
#pragma unroll
      for (int n = 0; n < 4; ++n)
        acc[m][n] = __builtin_amdgcn_mfma_f32_16x16x32_bf16(afr[m], bfr[n],
                                                            acc[m][n], 0, 0, 0);
    __syncthreads();
  }

  const int ocol = lane & 15;
  const int orow = (lane >> 4) * 4;
#pragma unroll
  for (int m = 0; m < 4; ++m) {
    const size_t rbase = (r0 + wr * 64 + m * 16 + orow) * 1024;
#pragma unroll
    for (int n = 0; n < 4; ++n) {
      float* o = out + rbase + (c0 + wc * 64 + n * 16 + ocol);
      o[0] = acc[m][n][0];
      o[1024] = acc[m][n][1];
      o[2048] = acc[m][n][2];
      o[3072] = acc[m][n][3];
    }
  }
}

// ---------------- fallback (R1's passing fused kernel) ------------------------
__global__ __launch_bounds__(256) void compute_M_fb(const float* __restrict__ W,
                                                    u16* __restrict__ Mb) {
  __shared__ float w1[32][64];
  __shared__ float w2[32][64];
  const int t = threadIdx.x;
  const int i0 = blockIdx.y * 64;
  const int j0 = blockIdx.x * 64;
  const int tx = t & 15, ty = t >> 4;
  float acc[4][4] = {};
  for (int u0 = 0; u0 < 1024; u0 += 32) {
    __syncthreads();
#pragma unroll
    for (int p = 0; p < 2; ++p) {
      int idx = p * 256 + t;
      int lu = idx >> 4, lc = (idx & 15) * 4;
      *(float4*)&w1[lu][lc] = *(const float4*)(W + (size_t)(u0 + lu) * 1024 + i0 + lc);
      *(float4*)&w2[lu][lc] = *(const float4*)(W + (size_t)(u0 + lu) * 1024 + j0 + lc);
    }
    __syncthreads();
#pragma unroll 8
    for (int u = 0; u < 32; ++u) {
      float4 a = *(const float4*)&w1[u][ty * 4];
      float4 b = *(const float4*)&w2[u][tx * 4];
      float av[4] = {a.x, a.y, a.z, a.w};
      float bv[4] = {b.x, b.y, b.z, b.w};
#pragma unroll
      for (int e = 0; e < 4; ++e)
#pragma unroll
        for (int f = 0; f < 4; ++f)
          acc[e][f] += av[e] * bv[f];
    }
  }
  const float s = 0.03125f;
#pragma unroll
  for (int e = 0; e < 4; ++e) {
    ushort4 v;
    v.x = f2bf(acc[e][0] * s);
    v.y = f2bf(acc[e][1] * s);
    v.z = f2bf(acc[e][2] * s);
    v.w = f2bf(acc[e][3] * s);
    *(ushort4*)(Mb + (size_t)(i0 + ty * 4 + e) * 1024 + j0 + tx * 4) = v;
  }
}

__global__ __launch_bounds__(256) void gemm_fused(const float* __restrict__ X,
                                                  const u16* __restrict__ Mb,
                                                  float* __restrict__ out) {
  __shared__ u16 lA[128 * 32];
  __shared__ u16 lB[128 * 32];
  const int p = blockIdx.x;
  const int wg = (p & 7) * 512 + (p >> 3);
  const int bm = wg >> 3;
  const int bn = wg & 7;
  const size_t r0 = (size_t)bm * 128;
  const int c0 = bn * 128;
  const int t = threadIdx.x;
  const int lane = t & 63;
  const int w = t >> 6;
  const int wr = w >> 1, wc = w & 1;
  const int ar_base = t >> 3;
  const int ac = t & 7;
  const int a_chunk = ac >> 1;
  const int a_half = ac & 1;
  const int fr = lane & 15;
  const int kc = lane >> 4;
  f32x4 acc[4][4] = {};
  for (int k0 = 0; k0 < 1024; k0 += 32) {
#pragma unroll
    for (int i = 0; i < 2; ++i) {
      const int slot0 = w * 128 + i * 64;
      const int slot = slot0 + lane;
      const int nr = slot >> 2;
      const int cc = (slot & 3) ^ ((nr >> 1) & 3);
      const char* g = (const char*)(Mb + (size_t)(c0 + nr) * 1024 + k0) + cc * 16;
      gload_lds16(g, (void*)(lB + slot0 * 8));
    }
#pragma unroll
    for (int q = 0; q < 4; ++q) {
      const int ar = q * 32 + ar_base;
      const float4 v = *(const float4*)(X + (r0 + ar) * 1024 + k0 + ac * 4);
      uint2 d;
      d.x = (u32)f2bf(v.x) | ((u32)f2bf(v.y) << 16);
      d.y = (u32)f2bf(v.z) | ((u32)f2bf(v.w) << 16);
      const int cs = a_chunk ^ ((ar >> 1) & 3);
      *(uint2*)&lA[ar * 32 + cs * 8 + a_half * 4] = d;
    }
    __syncthreads();
    bf16x8 afr[4], bfr[4];
#pragma unroll
    for (int m = 0; m < 4; ++m) {
      const int row = wr * 64 + m * 16 + fr;
      const int cs = kc ^ ((row >> 1) & 3);
      afr[m] = *(const bf16x8*)&lA[row * 32 + cs * 8];
    }
#pragma unroll
    for (int n = 0; n < 4; ++n) {
      const int row = wc * 64 + n * 16 + fr;
      const int cs = kc ^ ((row >> 1) & 3);
      bfr[n] = *(const bf16x8*)&lB[row * 32 + cs * 8];
    }
#pragma unroll
    for (int m = 0; m < 4; ++m)
#pragma unroll
      for (int n = 0; n < 4; ++n)
        acc[m][n] = __builtin_amdgcn_mfma_f32_16x16x32_bf16(afr[m], bfr[n],
                                                            acc[m][n], 0, 0, 0);
    __syncthreads();
  }
  const int ocol = lane & 15;
  const int orow = (lane >> 4) * 4;
#pragma unroll
  for (int m = 0; m < 4; ++m) {
    const size_t rbase = (r0 + wr * 64 + m * 16 + orow) * 1024;
#pragma unroll
    for (int n = 0; n < 4; ++n) {
      float* o = out + rbase + (c0 + wc * 64 + n * 16 + ocol);
      o[0] = acc[m][n][0];
      o[1024] = acc[m][n][1];
      o[2048] = acc[m][n][2];
      o[3072] = acc[m][n][3];
    }
  }
}

extern "C" void kernel_launch(void* const* d_in, const int* in_sizes, int n_in,
                              void* d_out, int out_size, void* d_ws, size_t ws_size,
                              hipStream_t stream) {
  const float* X = (const float*)d_in[0];
  const float* W = (const float*)d_in[1];
  float* out = (float*)d_out;
  u16* Mb = (u16*)d_ws;                                 // 2 MB
  u16* Xb = (u16*)((char*)d_ws + (size_t)(1 << 21));    // 128 MB

  const size_t need = (size_t)(1 << 21) + (size_t)64 * 1024 * 1024 * 2;
  if (ws_size >= need) {
    prep<<<2304, 256, 0, stream>>>(X, W, Xb, Mb);
    gemm_lds<<<4096, 256, 0, stream>>>(Xb, Mb, out);
  } else {
    compute_M_fb<<<dim3(16, 16), 256, 0, stream>>>(W, Mb);
    gemm_fused<<<4096, 256, 0, stream>>>(X, Mb, out);
  }
}

// Round 3
// 287.620 us; speedup vs baseline: 1.4697x; 1.4697x over previous
//
#include <hip/hip_runtime.h>

// out = X · M,  M = (W^T W)/32 (symmetric 1024x1024)
// X: 65536x1024 fp32.  W: 1024x1024 fp32.  out: 65536x1024 fp32.
// Path A (ws >= 130 MB): prep {M-tiles FIRST, then X->bf16 convert} ;
//   then deep-pipelined 256x256 GEMM (BK=32, 4-buf circular LDS, counted vmcnt,
//   raw s_barrier, setprio) — T2+T3+T4+T5 stack.
// Path B: R1's fused kernel (proven fallback).

typedef unsigned short u16;
typedef unsigned int u32;
typedef __bf16 bf16x8 __attribute__((ext_vector_type(8)));
typedef float f32x4 __attribute__((ext_vector_type(4)));

#define BAR() __builtin_amdgcn_s_barrier()
#define LGKM0() asm volatile("s_waitcnt lgkmcnt(0)" ::: "memory")
#define VMC(n) asm volatile("s_waitcnt vmcnt(" #n ")" ::: "memory")

__device__ __forceinline__ u16 f2bf(float f) {  // RNE fp32->bf16
  u32 u = __float_as_uint(f);
  u += 0x7fffu + ((u >> 16) & 1u);
  return (u16)(u >> 16);
}

__device__ __forceinline__ void gload_lds16(const void* g, void* l) {
  __builtin_amdgcn_global_load_lds((const __attribute__((address_space(1))) u32*)g,
                                   (__attribute__((address_space(3))) u32*)l,
                                   16, 0, 0);
}

// ---------------- prep: blocks [0,256) compute M FIRST; [256,2304) convert X --
__global__ __launch_bounds__(256) void prep(const float* __restrict__ X,
                                            const float* __restrict__ W,
                                            u16* __restrict__ Xb,
                                            u16* __restrict__ Mb) {
  __shared__ float w1[32][64];
  __shared__ float w2[32][64];
  const int t = threadIdx.x;
  if (blockIdx.x >= 256) {
    // convert 64M floats, float4 -> 4x bf16 (8B store), coalesced streaming
    const size_t stride = 2048 * 256;
    size_t idx = (size_t)(blockIdx.x - 256) * 256 + t;
#pragma unroll 4
    for (int it = 0; it < 32; ++it, idx += stride) {
      const float4 v = *(const float4*)(X + idx * 4);
      ushort4 d;
      d.x = f2bf(v.x); d.y = f2bf(v.y); d.z = f2bf(v.z); d.w = f2bf(v.w);
      *(ushort4*)(Xb + idx * 4) = d;
    }
    return;
  }
  // ---- M = (W^T W)/32, 64x64 tile per block (dispatched first => overlaps) --
  const int mb = blockIdx.x;
  const int i0 = (mb >> 4) * 64;
  const int j0 = (mb & 15) * 64;
  const int tx = t & 15, ty = t >> 4;
  float acc[4][4] = {};
  for (int u0 = 0; u0 < 1024; u0 += 32) {
    __syncthreads();
#pragma unroll
    for (int p = 0; p < 2; ++p) {
      int idx = p * 256 + t;
      int lu = idx >> 4, lc = (idx & 15) * 4;
      *(float4*)&w1[lu][lc] = *(const float4*)(W + (size_t)(u0 + lu) * 1024 + i0 + lc);
      *(float4*)&w2[lu][lc] = *(const float4*)(W + (size_t)(u0 + lu) * 1024 + j0 + lc);
    }
    __syncthreads();
#pragma unroll 8
    for (int u = 0; u < 32; ++u) {
      float4 a = *(const float4*)&w1[u][ty * 4];
      float4 b = *(const float4*)&w2[u][tx * 4];
      float av[4] = {a.x, a.y, a.z, a.w};
      float bv[4] = {b.x, b.y, b.z, b.w};
#pragma unroll
      for (int e = 0; e < 4; ++e)
#pragma unroll
        for (int f = 0; f < 4; ++f)
          acc[e][f] += av[e] * bv[f];
    }
  }
  const float s = 0.03125f;
#pragma unroll
  for (int e = 0; e < 4; ++e) {
    ushort4 v;
    v.x = f2bf(acc[e][0] * s);
    v.y = f2bf(acc[e][1] * s);
    v.z = f2bf(acc[e][2] * s);
    v.w = f2bf(acc[e][3] * s);
    *(ushort4*)(Mb + (size_t)(i0 + ty * 4 + e) * 1024 + j0 + tx * 4) = v;
  }
}

// ---------------- deep-pipelined GEMM: 256x256 tile, BK=32, 4-buf circular ----
// 512 threads = 8 waves (2x4). Wave tile 128x64 -> acc[8][4] 16x16 frags.
// Per K-tile (32 K): 2 phases x {ds_read, stage 2x gload_lds, s_barrier,
// lgkmcnt(0), setprio(1), 16 MFMA, setprio(0), s_barrier}.
// Stage schedule: phase 2j stages A of kt j+3, phase 2j+1 stages B of kt j+3
// into buf (j+3)&3 = (j-1)&3 (vacated at barrier ending iter j-1).
// Guard: vmcnt(8) at end of odd phase (kt j+2,j+3 = 8 loads allowed in flight)
// => kt j+1 fully landed before iter j+1 reads it. Tail: vmcnt(4)/vmcnt(0).
__global__ __launch_bounds__(512, 2) void gemm8(const u16* __restrict__ Xb,
                                                const u16* __restrict__ Mb,
                                                float* __restrict__ out) {
  __shared__ u16 lA[4][8192];  // 4 bufs x 256 rows x 32 bf16 = 64 KB
  __shared__ u16 lB[4][8192];  // 64 KB

  const int p = blockIdx.x;                    // nwg = 1024 (%8==0)
  const int wg = (p & 7) * 128 + (p >> 3);     // chunked XCD swizzle
  const int bm = wg >> 2;                      // 0..255
  const int bn = wg & 3;                       // 0..3  (A-panel shared by 4)
  const size_t r0 = (size_t)bm * 256;
  const int c0 = bn * 256;

  const int t = threadIdx.x;
  const int lane = t & 63;
  const int w = t >> 6;                        // 0..7
  const int wr = w >> 2, wc = w & 3;           // 2x4 wave grid
  const int fr = lane & 15;
  const int kc = lane >> 4;

  // staging geometry: unit = 128 rows x 32 cols = 8KB = 512 thread-slots x 16B
  const int srow = t >> 2;                     // 0..127
  const int scl = t & 3;
  const int scg = scl ^ ((srow >> 1) & 3);     // inverse chunk swizzle
  const u16* gA0 = Xb + (r0 + srow) * 1024 + scg * 8;
  const u16* gA1 = Xb + (r0 + 128 + srow) * 1024 + scg * 8;
  const u16* gB0 = Mb + (size_t)(c0 + srow) * 1024 + scg * 8;       // M symmetric
  const u16* gB1 = Mb + (size_t)(c0 + 128 + srow) * 1024 + scg * 8;
  const int sl0 = w * 512;                     // wave-uniform LDS slot base (u16)
  const int sl1 = 4096 + w * 512;

  f32x4 acc[8][4] = {};

  // ---- prologue: stage kt 0,1,2 (12 loads/thread); kt0 landed at vmcnt(8) ----
#pragma unroll
  for (int jt = 0; jt < 3; ++jt) {
    gload_lds16(gA0 + jt * 32, (void*)&lA[jt][sl0]);
    gload_lds16(gA1 + jt * 32, (void*)&lA[jt][sl1]);
    gload_lds16(gB0 + jt * 32, (void*)&lB[jt][sl0]);
    gload_lds16(gB1 + jt * 32, (void*)&lB[jt][sl1]);
  }
  VMC(8);
  BAR();

  for (int j = 0; j < 32; ++j) {
    const int rb = j & 3;
    const int sb = (j + 3) & 3;
    const u16* bA = &lA[rb][0];
    const u16* bB = &lB[rb][0];
    const int ko = (j + 3) * 32;
    const bool st = (j + 3) < 32;

    bf16x8 af[4], bf[4];
    // ================= even phase: acc[0..3][0..3] =================
#pragma unroll
    for (int m = 0; m < 4; ++m) {
      const int row = wr * 128 + m * 16 + fr;
      const int cs = kc ^ ((row >> 1) & 3);
      af[m] = *(const bf16x8*)&bA[row * 32 + cs * 8];
    }
#pragma unroll
    for (int n = 0; n < 4; ++n) {
      const int row = wc * 64 + n * 16 + fr;
      const int cs = kc ^ ((row >> 1) & 3);
      bf[n] = *(const bf16x8*)&bB[row * 32 + cs * 8];
    }
    if (st) {
      gload_lds16(gA0 + ko, (void*)&lA[sb][sl0]);
      gload_lds16(gA1 + ko, (void*)&lA[sb][sl1]);
    }
    BAR();
    LGKM0();
    __builtin_amdgcn_s_setprio(1);
#pragma unroll
    for (int m = 0; m < 4; ++m)
#pragma unroll
      for (int n = 0; n < 4; ++n)
        acc[m][n] = __builtin_amdgcn_mfma_f32_16x16x32_bf16(af[m], bf[n],
                                                            acc[m][n], 0, 0, 0);
    __builtin_amdgcn_s_setprio(0);
    BAR();
    // ================= odd phase: acc[4..7][0..3] (reuse bf) =================
#pragma unroll
    for (int m = 0; m < 4; ++m) {
      const int row = wr * 128 + (m + 4) * 16 + fr;
      const int cs = kc ^ ((row >> 1) & 3);
      af[m] = *(const bf16x8*)&bA[row * 32 + cs * 8];
    }
    if (st) {
      gload_lds16(gB0 + ko, (void*)&lB[sb][sl0]);
      gload_lds16(gB1 + ko, (void*)&lB[sb][sl1]);
    }
    BAR();
    LGKM0();
    __builtin_amdgcn_s_setprio(1);
#pragma unroll
    for (int m = 0; m < 4; ++m)
#pragma unroll
      for (int n = 0; n < 4; ++n)
        acc[m + 4][n] = __builtin_amdgcn_mfma_f32_16x16x32_bf16(af[m], bf[n],
                                                                acc[m + 4][n], 0, 0, 0);
    __builtin_amdgcn_s_setprio(0);
    // guard next iteration's reads: kt j+1 must be landed
    if (j < 29) {
      VMC(8);
    } else if (j == 29) {
      VMC(4);
    } else if (j == 30) {
      VMC(0);
    }
    BAR();
  }

  // ---- epilogue: C layout col=lane&15, row=(lane>>4)*4+reg ----
  const int ocol = lane & 15;
  const int orow = (lane >> 4) * 4;
#pragma unroll
  for (int m = 0; m < 8; ++m) {
    const size_t rbase = (r0 + wr * 128 + m * 16 + orow) * 1024;
#pragma unroll
    for (int n = 0; n < 4; ++n) {
      float* o = out + rbase + (c0 + wc * 64 + n * 16 + ocol);
      o[0] = acc[m][n][0];
      o[1024] = acc[m][n][1];
      o[2048] = acc[m][n][2];
      o[3072] = acc[m][n][3];
    }
  }
}

// ---------------- fallback (R1's passing fused kernel) ------------------------
__global__ __launch_bounds__(256) void compute_M_fb(const float* __restrict__ W,
                                                    u16* __restrict__ Mb) {
  __shared__ float w1[32][64];
  __shared__ float w2[32][64];
  const int t = threadIdx.x;
  const int i0 = blockIdx.y * 64;
  const int j0 = blockIdx.x * 64;
  const int tx = t & 15, ty = t >> 4;
  float acc[4][4] = {};
  for (int u0 = 0; u0 < 1024; u0 += 32) {
    __syncthreads();
#pragma unroll
    for (int p = 0; p < 2; ++p) {
      int idx = p * 256 + t;
      int lu = idx >> 4, lc = (idx & 15) * 4;
      *(float4*)&w1[lu][lc] = *(const float4*)(W + (size_t)(u0 + lu) * 1024 + i0 + lc);
      *(float4*)&w2[lu][lc] = *(const float4*)(W + (size_t)(u0 + lu) * 1024 + j0 + lc);
    }
    __syncthreads();
#pragma unroll 8
    for (int u = 0; u < 32; ++u) {
      float4 a = *(const float4*)&w1[u][ty * 4];
      float4 b = *(const float4*)&w2[u][tx * 4];
      float av[4] = {a.x, a.y, a.z, a.w};
      float bv[4] = {b.x, b.y, b.z, b.w};
#pragma unroll
      for (int e = 0; e < 4; ++e)
#pragma unroll
        for (int f = 0; f < 4; ++f)
          acc[e][f] += av[e] * bv[f];
    }
  }
  const float s = 0.03125f;
#pragma unroll
  for (int e = 0; e < 4; ++e) {
    ushort4 v;
    v.x = f2bf(acc[e][0] * s);
    v.y = f2bf(acc[e][1] * s);
    v.z = f2bf(acc[e][2] * s);
    v.w = f2bf(acc[e][3] * s);
    *(ushort4*)(Mb + (size_t)(i0 + ty * 4 + e) * 1024 + j0 + tx * 4) = v;
  }
}

__global__ __launch_bounds__(256) void gemm_fused(const float* __restrict__ X,
                                                  const u16* __restrict__ Mb,
                                                  float* __restrict__ out) {
  __shared__ u16 lA[128 * 32];
  __shared__ u16 lB[128 * 32];
  const int p = blockIdx.x;
  const int wg = (p & 7) * 512 + (p >> 3);
  const int bm = wg >> 3;
  const int bn = wg & 7;
  const size_t r0 = (size_t)bm * 128;
  const int c0 = bn * 128;
  const int t = threadIdx.x;
  const int lane = t & 63;
  const int w = t >> 6;
  const int wr = w >> 1, wc = w & 1;
  const int ar_base = t >> 3;
  const int ac = t & 7;
  const int a_chunk = ac >> 1;
  const int a_half = ac & 1;
  const int fr = lane & 15;
  const int kc = lane >> 4;
  f32x4 acc[4][4] = {};
  for (int k0 = 0; k0 < 1024; k0 += 32) {
#pragma unroll
    for (int i = 0; i < 2; ++i) {
      const int slot0 = w * 128 + i * 64;
      const int slot = slot0 + lane;
      const int nr = slot >> 2;
      const int cc = (slot & 3) ^ ((nr >> 1) & 3);
      const char* g = (const char*)(Mb + (size_t)(c0 + nr) * 1024 + k0) + cc * 16;
      gload_lds16(g, (void*)(lB + slot0 * 8));
    }
#pragma unroll
    for (int q = 0; q < 4; ++q) {
      const int ar = q * 32 + ar_base;
      const float4 v = *(const float4*)(X + (r0 + ar) * 1024 + k0 + ac * 4);
      uint2 d;
      d.x = (u32)f2bf(v.x) | ((u32)f2bf(v.y) << 16);
      d.y = (u32)f2bf(v.z) | ((u32)f2bf(v.w) << 16);
      const int cs = a_chunk ^ ((ar >> 1) & 3);
      *(uint2*)&lA[ar * 32 + cs * 8 + a_half * 4] = d;
    }
    __syncthreads();
    bf16x8 afr[4], bfr[4];
#pragma unroll
    for (int m = 0; m < 4; ++m) {
      const int row = wr * 64 + m * 16 + fr;
      const int cs = kc ^ ((row >> 1) & 3);
      afr[m] = *(const bf16x8*)&lA[row * 32 + cs * 8];
    }
#pragma unroll
    for (int n = 0; n < 4; ++n) {
      const int row = wc * 64 + n * 16 + fr;
      const int cs = kc ^ ((row >> 1) & 3);
      bfr[n] = *(const bf16x8*)&lB[row * 32 + cs * 8];
    }
#pragma unroll
    for (int m = 0; m < 4; ++m)
#pragma unroll
      for (int n = 0; n < 4; ++n)
        acc[m][n] = __builtin_amdgcn_mfma_f32_16x16x32_bf16(afr[m], bfr[n],
                                                            acc[m][n], 0, 0, 0);
    __syncthreads();
  }
  const int ocol = lane & 15;
  const int orow = (lane >> 4) * 4;
#pragma unroll
  for (int m = 0; m < 4; ++m) {
    const size_t rbase = (r0 + wr * 64 + m * 16 + orow) * 1024;
#pragma unroll
    for (int n = 0; n < 4; ++n) {
      float* o = out + rbase + (c0 + wc * 64 + n * 16 + ocol);
      o[0] = acc[m][n][0];
      o[1024] = acc[m][n][1];
      o[2048] = acc[m][n][2];
      o[3072] = acc[m][n][3];
    }
  }
}

extern "C" void kernel_launch(void* const* d_in, const int* in_sizes, int n_in,
                              void* d_out, int out_size, void* d_ws, size_t ws_size,
                              hipStream_t stream) {
  const float* X = (const float*)d_in[0];
  const float* W = (const float*)d_in[1];
  float* out = (float*)d_out;
  u16* Mb = (u16*)d_ws;                                 // 2 MB
  u16* Xb = (u16*)((char*)d_ws + (size_t)(1 << 21));    // 128 MB

  const size_t need = (size_t)(1 << 21) + (size_t)64 * 1024 * 1024 * 2;
  if (ws_size >= need) {
    prep<<<2304, 256, 0, stream>>>(X, W, Xb, Mb);
    gemm8<<<1024, 512, 0, stream>>>(Xb, Mb, out);
  } else {
    compute_M_fb<<<dim3(16, 16), 256, 0, stream>>>(W, Mb);
    gemm_fused<<<4096, 256, 0, stream>>>(X, Mb, out);
  }
}

// Round 4
// 264.918 us; speedup vs baseline: 1.5956x; 1.0857x over previous
//
#include <hip/hip_runtime.h>

// out = X · M,  M = (W^T W)/32 (symmetric 1024x1024)
// X: 65536x1024 fp32.  W: 1024x1024 fp32.  out: 65536x1024 fp32.
// K1: compute_M (VALU outer-product, 256 blocks, ~30us)
// K2: gemm8f — 256x256 tile, BK=32, 8 waves, 4-buf circular LDS, counted vmcnt,
//     raw s_barrier, setprio; A staged fp32->bf16 IN-KERNEL (asm loads + cast +
//     swizzled ds_write), B staged via global_load_lds. No Xb pass.

typedef unsigned short u16;
typedef unsigned int u32;
typedef __bf16 bf16x8 __attribute__((ext_vector_type(8)));
typedef float f32x4 __attribute__((ext_vector_type(4)));

#define BAR() __builtin_amdgcn_s_barrier()
#define LGKM0() asm volatile("s_waitcnt lgkmcnt(0)" ::: "memory")
#define VMC(n) asm volatile("s_waitcnt vmcnt(" #n ")" ::: "memory")
#define SCHED0() __builtin_amdgcn_sched_barrier(0)

__device__ __forceinline__ u16 f2bf(float f) {  // RNE fp32->bf16 (M kernel)
  u32 u = __float_as_uint(f);
  u += 0x7fffu + ((u >> 16) & 1u);
  return (u16)(u >> 16);
}

__device__ __forceinline__ void gload_lds16(const void* g, void* l) {
  __builtin_amdgcn_global_load_lds((const __attribute__((address_space(1))) u32*)g,
                                   (__attribute__((address_space(3))) u32*)l,
                                   16, 0, 0);
}

// two 16B fp32 loads at p and p+16B; asm so issue order/count is exact
// (vmcnt bookkeeping) — compiler does NOT track these; VMC guards arrival.
__device__ __forceinline__ void load2x16(const float* p, f32x4& a, f32x4& b) {
  asm volatile("global_load_dwordx4 %0, %2, off\n\t"
               "global_load_dwordx4 %1, %2, off offset:16"
               : "=&v"(a), "=&v"(b)
               : "v"(p)
               : "memory");
}

__device__ __forceinline__ bf16x8 cvt8(f32x4 a, f32x4 b) {  // scalar casts -> packed cvt
  bf16x8 h;
  h[0] = (__bf16)a[0]; h[1] = (__bf16)a[1]; h[2] = (__bf16)a[2]; h[3] = (__bf16)a[3];
  h[4] = (__bf16)b[0]; h[5] = (__bf16)b[1]; h[6] = (__bf16)b[2]; h[7] = (__bf16)b[3];
  return h;
}

// ---------------- K1: M = (W^T W)/32, 64x64 tile per block --------------------
__global__ __launch_bounds__(256) void compute_M(const float* __restrict__ W,
                                                 u16* __restrict__ Mb) {
  __shared__ float w1[32][64];
  __shared__ float w2[32][64];
  const int t = threadIdx.x;
  const int i0 = blockIdx.y * 64;
  const int j0 = blockIdx.x * 64;
  const int tx = t & 15, ty = t >> 4;
  float acc[4][4] = {};
  for (int u0 = 0; u0 < 1024; u0 += 32) {
    __syncthreads();
#pragma unroll
    for (int p = 0; p < 2; ++p) {
      int idx = p * 256 + t;
      int lu = idx >> 4, lc = (idx & 15) * 4;
      *(float4*)&w1[lu][lc] = *(const float4*)(W + (size_t)(u0 + lu) * 1024 + i0 + lc);
      *(float4*)&w2[lu][lc] = *(const float4*)(W + (size_t)(u0 + lu) * 1024 + j0 + lc);
    }
    __syncthreads();
#pragma unroll 8
    for (int u = 0; u < 32; ++u) {
      float4 a = *(const float4*)&w1[u][ty * 4];
      float4 b = *(const float4*)&w2[u][tx * 4];
      float av[4] = {a.x, a.y, a.z, a.w};
      float bv[4] = {b.x, b.y, b.z, b.w};
#pragma unroll
      for (int e = 0; e < 4; ++e)
#pragma unroll
        for (int f = 0; f < 4; ++f)
          acc[e][f] += av[e] * bv[f];
    }
  }
  const float s = 0.03125f;
#pragma unroll
  for (int e = 0; e < 4; ++e) {
    ushort4 v;
    v.x = f2bf(acc[e][0] * s);
    v.y = f2bf(acc[e][1] * s);
    v.z = f2bf(acc[e][2] * s);
    v.w = f2bf(acc[e][3] * s);
    *(ushort4*)(Mb + (size_t)(i0 + ty * 4 + e) * 1024 + j0 + tx * 4) = v;
  }
}

// ---------------- K2: fused-cvt deep-pipelined GEMM ---------------------------
// vmcnt invariant (per-thread VMEM issue order per iter j:
//   even: [4 fp32 loads kt j+4]   odd: [2 B gloads kt j+3]):
// after iter j's even-phase VMC(2): outstanding ⊆ {B_{j+2}} — forces
// fp32_{j+3} (cvt'd now) and B_{j+1} (read next iter). VMC(0) at j=0 (startup)
// and j=30 (B_31 tail). A ds_writes at iter j target buf (j+3)&3, freed at
// iter j-1's end-barrier; each wave LGKM0s before its MFMA => writes complete
// >=2 barriers before iter j+3's readers.
__global__ __launch_bounds__(512, 2) void gemm8f(const float* __restrict__ X,
                                                 const u16* __restrict__ Mb,
                                                 float* __restrict__ out) {
  __shared__ u16 lA[4][8192];  // 4 bufs x 256 rows x 32 bf16 = 64 KB
  __shared__ u16 lB[4][8192];

  const int p = blockIdx.x;                    // nwg = 1024 (%8==0)
  const int wg = (p & 7) * 128 + (p >> 3);     // chunked XCD swizzle
  const int bm = wg >> 2;
  const int bn = wg & 3;                       // A-panel shared by 4 neighbors
  const size_t r0 = (size_t)bm * 256;
  const int c0 = bn * 256;

  const int t = threadIdx.x;
  const int lane = t & 63;
  const int w = t >> 6;
  const int wr = w >> 2, wc = w & 3;           // 2x4 wave grid, wave tile 128x64
  const int fr = lane & 15;
  const int kc = lane >> 4;

  // staging geometry: thread covers rows {srow, srow+128}, chunk scl (8 elems)
  const int srow = t >> 2;                     // 0..127
  const int scl = t & 3;
  const int csw = scl ^ ((srow >> 1) & 3);     // swizzled LDS chunk (same for +128)
  // A (fp32, cvt path): natural global chunk, swizzled ds_write
  const float* aLo = X + (r0 + srow) * 1024 + scl * 8;
  const float* aHi = X + (r0 + 128 + srow) * 1024 + scl * 8;
  u16* wLo = &lA[0][srow * 32 + csw * 8];
  u16* wHi = &lA[0][(srow + 128) * 32 + csw * 8];
  // B (bf16 Mb, gload_lds path): inverse-swizzled global chunk, linear LDS
  const int scg = csw;
  const u16* gB0 = Mb + (size_t)(c0 + srow) * 1024 + scg * 8;
  const u16* gB1 = Mb + (size_t)(c0 + 128 + srow) * 1024 + scg * 8;
  const int sl0 = w * 512;
  const int sl1 = 4096 + w * 512;

  f32x4 acc[8][4] = {};
  f32x4 q0a, q0b, q0c, q0d, q1a, q1b, q1c, q1d, q2a, q2b, q2c, q2d;
  f32x4 pfa, pfb, pfc, pfd;  // pending fp32 generation (kt j+3 at iter j)

  // ---- prologue: A kt0-2 (12 ld), B kt0-2 (6 gload), A kt3 (4 ld) = 22 ----
  load2x16(aLo + 0 * 32, q0a, q0b);  load2x16(aHi + 0 * 32, q0c, q0d);
  load2x16(aLo + 1 * 32, q1a, q1b);  load2x16(aHi + 1 * 32, q1c, q1d);
  load2x16(aLo + 2 * 32, q2a, q2b);  load2x16(aHi + 2 * 32, q2c, q2d);
#pragma unroll
  for (int jt = 0; jt < 3; ++jt) {
    gload_lds16(gB0 + jt * 32, (void*)&lB[jt][sl0]);
    gload_lds16(gB1 + jt * 32, (void*)&lB[jt][sl1]);
  }
  load2x16(aLo + 3 * 32, pfa, pfb);  load2x16(aHi + 3 * 32, pfc, pfd);
  VMC(8);   // forces fp32 kt0-2 (12) + B kt0 (2); leaves B kt1,2 + fp32 kt3 = 8
  SCHED0();
  *(bf16x8*)(wLo + 0 * 8192) = cvt8(q0a, q0b);
  *(bf16x8*)(wHi + 0 * 8192) = cvt8(q0c, q0d);
  *(bf16x8*)(wLo + 1 * 8192) = cvt8(q1a, q1b);
  *(bf16x8*)(wHi + 1 * 8192) = cvt8(q1c, q1d);
  *(bf16x8*)(wLo + 2 * 8192) = cvt8(q2a, q2b);
  *(bf16x8*)(wHi + 2 * 8192) = cvt8(q2c, q2d);
  LGKM0();
  BAR();

  for (int j = 0; j < 32; ++j) {
    const int rb = j & 3;
    const int sb = (j + 3) & 3;
    const u16* bA = &lA[rb][0];
    const u16* bB = &lB[rb][0];

    // ================= even phase =================
    if (j == 0 || j == 30) { VMC(0); } else { VMC(2); }
    SCHED0();
    if (j <= 28) {  // cvt pending gen (kt j+3) -> buf sb
      *(bf16x8*)(wLo + sb * 8192) = cvt8(pfa, pfb);
      *(bf16x8*)(wHi + sb * 8192) = cvt8(pfc, pfd);
    }
    bf16x8 af[4], bf[4];
#pragma unroll
    for (int m = 0; m < 4; ++m) {
      const int row = wr * 128 + m * 16 + fr;
      const int cs = kc ^ ((row >> 1) & 3);
      af[m] = *(const bf16x8*)&bA[row * 32 + cs * 8];
    }
#pragma unroll
    for (int n = 0; n < 4; ++n) {
      const int row = wc * 64 + n * 16 + fr;
      const int cs = kc ^ ((row >> 1) & 3);
      bf[n] = *(const bf16x8*)&bB[row * 32 + cs * 8];
    }
    if (j <= 27) {  // issue fp32 loads for kt j+4
      load2x16(aLo + (j + 4) * 32, pfa, pfb);
      load2x16(aHi + (j + 4) * 32, pfc, pfd);
    }
    BAR();
    LGKM0();
    __builtin_amdgcn_s_setprio(1);
#pragma unroll
    for (int m = 0; m < 4; ++m)
#pragma unroll
      for (int n = 0; n < 4; ++n)
        acc[m][n] = __builtin_amdgcn_mfma_f32_16x16x32_bf16(af[m], bf[n],
                                                            acc[m][n], 0, 0, 0);
    __builtin_amdgcn_s_setprio(0);
    BAR();
    // ================= odd phase (reuse bf) =================
#pragma unroll
    for (int m = 0; m < 4; ++m) {
      const int row = wr * 128 + (m + 4) * 16 + fr;
      const int cs = kc ^ ((row >> 1) & 3);
      af[m] = *(const bf16x8*)&bA[row * 32 + cs * 8];
    }
    if (j <= 28) {  // stage B kt j+3 -> buf sb
      gload_lds16(gB0 + (j + 3) * 32, (void*)&lB[sb][sl0]);
      gload_lds16(gB1 + (j + 3) * 32, (void*)&lB[sb][sl1]);
    }
    BAR();
    LGKM0();
    __builtin_amdgcn_s_setprio(1);
#pragma unroll
    for (int m = 0; m < 4; ++m)
#pragma unroll
      for (int n = 0; n < 4; ++n)
        acc[m + 4][n] = __builtin_amdgcn_mfma_f32_16x16x32_bf16(af[m], bf[n],
                                                                acc[m + 4][n], 0, 0, 0);
    __builtin_amdgcn_s_setprio(0);
    BAR();
  }

  // ---- epilogue: C layout col=lane&15, row=(lane>>4)*4+reg ----
  const int ocol = lane & 15;
  const int orow = (lane >> 4) * 4;
#pragma unroll
  for (int m = 0; m < 8; ++m) {
    const size_t rbase = (r0 + wr * 128 + m * 16 + orow) * 1024;
#pragma unroll
    for (int n = 0; n < 4; ++n) {
      float* o = out + rbase + (c0 + wc * 64 + n * 16 + ocol);
      o[0] = acc[m][n][0];
      o[1024] = acc[m][n][1];
      o[2048] = acc[m][n][2];
      o[3072] = acc[m][n][3];
    }
  }
}

extern "C" void kernel_launch(void* const* d_in, const int* in_sizes, int n_in,
                              void* d_out, int out_size, void* d_ws, size_t ws_size,
                              hipStream_t stream) {
  const float* X = (const float*)d_in[0];
  const float* W = (const float*)d_in[1];
  float* out = (float*)d_out;
  u16* Mb = (u16*)d_ws;  // 2 MB scratch

  compute_M<<<dim3(16, 16), 256, 0, stream>>>(W, Mb);
  gemm8f<<<1024, 512, 0, stream>>>(X, Mb, out);
}